// Round 2
// baseline (477.405 us; speedup 1.0000x reference)
//
#include <hip/hip_runtime.h>
#include <math.h>

// Problem constants (match reference)
constexpr int N = 1024;
constexpr int D = 128;
constexpr int S = 200;

// One thread per scalar (n, d) chain: 131072 threads = 512 blocks x 256
// = 2 blocks/CU = 8 waves/CU (2/SIMD) on MI355X's 256 CUs.
// Unroll-8: the 8 noise loads per unrolled body are chain-independent,
// giving ~8 outstanding 256B wave-loads -> 16 KB in flight per CU.
__global__ __launch_bounds__(256, 2) void langevin_kernel(
    const float* __restrict__ x0,
    const float* __restrict__ y0,
    const float* __restrict__ mean,
    const float* __restrict__ var,
    const float* __restrict__ gammas,
    const float* __restrict__ noise,   // [S][N][D]
    float* __restrict__ x_tot,         // [N][S][D]
    float* __restrict__ y_tot,         // [N][S][D]
    float* __restrict__ outp,          // [N][S][D]
    float* __restrict__ steps)         // [N][S]
{
    __shared__ float sg[S];
    __shared__ float ss[S];
    for (int i = threadIdx.x; i < S; i += 256) {
        float g = gammas[i];
        sg[i] = g;
        ss[i] = sqrtf(2.0f * g);
    }
    __syncthreads();

    const int idx = blockIdx.x * 256 + threadIdx.x;  // 0 .. N*D-1
    const int n   = idx >> 7;                        // idx / D
    const int d   = idx & (D - 1);                   // idx % D

    float x       = x0[idx];
    const float y = y0[idx];
    const float m = mean[d];
    const float iv = 1.0f / var[d];

    const float* zp = noise + idx;                   // + k*N*D per step
    const size_t base = (size_t)n * (S * D) + d;     // + k*D per step
    float* xq = x_tot + base;
    float* yq = y_tot + base;
    float* oq = outp  + base;
    float* sq = steps + (size_t)n * S;

    #pragma unroll 8
    for (int k = 0; k < S; ++k) {
        const float g = sg[k];
        const float s = ss[k];
        const float z = __builtin_nontemporal_load(zp + (size_t)k * (N * D));

        const float gv = g * iv;
        // t_old = x - (g/v)*(x-m)
        const float to = fmaf(-gv, x - m, x);
        // x_new = t_old + sqrt(2g)*z
        x = fmaf(s, z, to);
        // t_new = x_new - (g/v)*(x_new-m)
        const float tn = fmaf(-gv, x - m, x);
        const float o  = to - tn;

        __builtin_nontemporal_store(x, xq + (size_t)k * D);
        __builtin_nontemporal_store(y, yq + (size_t)k * D);
        __builtin_nontemporal_store(o, oq + (size_t)k * D);
        if (d == 0) __builtin_nontemporal_store((float)k, sq + k);
    }
}

extern "C" void kernel_launch(void* const* d_in, const int* in_sizes, int n_in,
                              void* d_out, int out_size, void* d_ws, size_t ws_size,
                              hipStream_t stream)
{
    const float* x0     = (const float*)d_in[0];
    const float* y0     = (const float*)d_in[1];
    const float* mean   = (const float*)d_in[2];
    const float* var    = (const float*)d_in[3];
    const float* gammas = (const float*)d_in[4];
    const float* noise  = (const float*)d_in[5];

    float* x_tot = (float*)d_out;                    // N*S*D
    float* y_tot = x_tot + (size_t)N * S * D;        // N*S*D
    float* outp  = y_tot + (size_t)N * S * D;        // N*S*D
    float* steps = outp  + (size_t)N * S * D;        // N*S

    dim3 grid((N * D) / 256);  // 512 blocks
    dim3 block(256);
    langevin_kernel<<<grid, block, 0, stream>>>(
        x0, y0, mean, var, gammas, noise, x_tot, y_tot, outp, steps);
}